// Round 4
// baseline (6083.384 us; speedup 1.0000x reference)
//
#include <hip/hip_runtime.h>

#define NPTS 8192
#define SPTS 2048
#define KS 32
#define CF 64
#define BQ 4
#define FPS_T 512
#define CPT 16               // sorted slots per thread
#define NCELL 512            // 8x8x8 spatial grid

#define OFF_GROUPED 24576                    // B*S*3
#define GROUPED_SZ  17563648                 // B*67*S*K
#define OFF_FPSIDX  (OFF_GROUPED + GROUPED_SZ)

typedef __attribute__((ext_vector_type(4))) float vf4;
typedef unsigned long long u64;

// ---------------- FPS: one block per batch; spatial-sort + box-pruned updates ----------------
// d_ws usage: vf4 sorted[B][NPTS] = 512 KB
__global__ __launch_bounds__(FPS_T)
void fps_kernel(const float* __restrict__ xyz, float* __restrict__ out,
                float* __restrict__ ws)
{
#pragma clang fp contract(off)
    __shared__ int hist[NCELL];
    __shared__ int scanbuf[NCELL];
    __shared__ int offs[NCELL];
    __shared__ u64 slots[2][8];

    const int b    = blockIdx.x;
    const int tid  = threadIdx.x;
    const int wv   = tid >> 6;
    const int lane = tid & 63;
    const float* xb = xyz + (size_t)b * (NPTS * 3);
    vf4* sorted = (vf4*)ws + (size_t)b * NPTS;

    // ---------- phase 1: counting sort by 8x8x8 cell ----------
    hist[tid] = 0;
    // thread owns original points [tid*16, tid*16+16): 48 contiguous floats = 12 vf4
    float a[3 * CPT];
    {
        const vf4* xb4 = (const vf4*)xb;
        vf4* av = (vf4*)a;
#pragma unroll
        for (int k = 0; k < 12; ++k) av[k] = xb4[tid * 12 + k];
    }
    int cell[CPT];
    __syncthreads();   // hist zero-init visible
#pragma unroll
    for (int j = 0; j < CPT; ++j) {
        const float x = a[3 * j + 0], y = a[3 * j + 1], z = a[3 * j + 2];
        int ix = (int)((x + 5.0f) * 0.8f); ix = ix < 0 ? 0 : (ix > 7 ? 7 : ix);
        int iy = (int)((y + 5.0f) * 0.8f); iy = iy < 0 ? 0 : (iy > 7 ? 7 : iy);
        int iz = (int)((z + 5.0f) * 0.8f); iz = iz < 0 ? 0 : (iz > 7 ? 7 : iz);
        cell[j] = (ix << 6) | (iy << 3) | iz;
        atomicAdd(&hist[cell[j]], 1);
    }
    __syncthreads();
    // exclusive scan over 512 bins (Hillis-Steele)
    {
        const int v = hist[tid];
        scanbuf[tid] = v;
        __syncthreads();
        for (int s = 1; s < NCELL; s <<= 1) {
            const int t = (tid >= s) ? scanbuf[tid - s] : 0;
            __syncthreads();
            scanbuf[tid] += t;
            __syncthreads();
        }
        offs[tid] = scanbuf[tid] - v;
    }
    __syncthreads();
    // scatter (intra-cell order nondeterministic; output invariant to it)
#pragma unroll
    for (int j = 0; j < CPT; ++j) {
        const int pos = atomicAdd(&offs[cell[j]], 1);
        vf4 o;
        o.x = a[3 * j + 0]; o.y = a[3 * j + 1]; o.z = a[3 * j + 2];
        o.w = __int_as_float(tid * CPT + j);
        sorted[pos] = o;
    }
    __threadfence();
    __syncthreads();
    __threadfence();

    // ---------- phase 2: per-thread bbox over its 16 sorted slots ----------
    float bxl = 1e30f, bxh = -1e30f, byl = 1e30f, byh = -1e30f, bzl = 1e30f, bzh = -1e30f;
#pragma unroll
    for (int k = 0; k < CPT; ++k) {
        const vf4 p = sorted[tid * CPT + k];
        bxl = fminf(bxl, p.x); bxh = fmaxf(bxh, p.x);
        byl = fminf(byl, p.y); byh = fmaxf(byh, p.y);
        bzl = fminf(bzl, p.z); bzh = fmaxf(bzh, p.z);
    }
    float md[CPT];
#pragma unroll
    for (int k = 0; k < CPT; ++k) md[k] = 1e10f;
    float tmax = 1e10f;
    u64 tkey = 0;   // set at i=1 (box test can never skip while tmax==1e10)

    float* newxyz = out;
    float* fpsidx = out + OFF_FPSIDX;

    // iteration 0: center = original point 0
    float qx = xb[0], qy = xb[1], qz = xb[2];
    if (tid == 0) {
        fpsidx[(size_t)b * SPTS + 0] = 0.0f;
        newxyz[(size_t)b * SPTS * 3 + 0] = qx;
        newxyz[(size_t)b * SPTS * 3 + 1] = qy;
        newxyz[(size_t)b * SPTS * 3 + 2] = qz;
    }

    // ---------- phase 3: FPS iterations ----------
    for (int i = 1; i < SPTS; ++i) {
        // conservative box-distance prune: skip => no md in chunk can change
        const float ddx = fmaxf(fmaxf(bxl - qx, qx - bxh), 0.0f);
        const float ddy = fmaxf(fmaxf(byl - qy, qy - byh), 0.0f);
        const float ddz = fmaxf(fmaxf(bzl - qz, qz - bzh), 0.0f);
        const float d2b = ddx * ddx + ddy * ddy + ddz * ddz;

        if (d2b * 0.999f < tmax) {
            float bd = -1.0f; int borig = 0, bslot = 0;
#pragma unroll
            for (int k = 0; k < CPT; ++k) {
                const vf4 p = sorted[tid * CPT + k];
                const float dx = p.x - qx;
                const float dy = p.y - qy;
                const float dz = p.z - qz;
                const float d  = (dx * dx + dy * dy) + dz * dz;  // exact ref order
                const float m  = fminf(md[k], d);
                md[k] = m;
                const int orig = __float_as_int(p.w);
                if (m > bd || (m == bd && orig < borig)) {
                    bd = m; borig = orig; bslot = tid * CPT + k;
                }
            }
            tmax = bd;
            tkey = ((u64)__float_as_uint(bd) << 32) |
                   ((u64)(unsigned)(NPTS - 1 - borig) << 13) |
                   (u64)(unsigned)bslot;
        }

        // 64-lane butterfly max on cached keys
        u64 wk = tkey;
#pragma unroll
        for (int off = 32; off > 0; off >>= 1) {
            const u64 o = __shfl_xor(wk, off);
            if (o > wk) wk = o;
        }
        if (lane == 0) slots[i & 1][wv] = wk;
        __syncthreads();                     // the only barrier per iteration

        u64 s0 = slots[i & 1][0], s1 = slots[i & 1][1];
        u64 s2 = slots[i & 1][2], s3 = slots[i & 1][3];
        u64 s4 = slots[i & 1][4], s5 = slots[i & 1][5];
        u64 s6 = slots[i & 1][6], s7 = slots[i & 1][7];
        s0 = s0 > s1 ? s0 : s1;  s2 = s2 > s3 ? s2 : s3;
        s4 = s4 > s5 ? s4 : s5;  s6 = s6 > s7 ? s6 : s7;
        s0 = s0 > s2 ? s0 : s2;  s4 = s4 > s6 ? s4 : s6;
        const u64 g = s0 > s4 ? s0 : s4;

        const int winpos = (int)(g & 8191ull);
        const int worig  = (NPTS - 1) - (int)((g >> 13) & 8191ull);

        const vf4 q = sorted[winpos];        // lane-uniform broadcast load
        qx = q.x; qy = q.y; qz = q.z;

        if (tid == 0) {
            fpsidx[(size_t)b * SPTS + i] = (float)worig;
            const size_t o = ((size_t)b * SPTS + i) * 3;
            newxyz[o + 0] = qx; newxyz[o + 1] = qy; newxyz[o + 2] = qz;
        }
    }
}

// ---------------- ball query + grouping: one wave per center ----------------
__global__ __launch_bounds__(256)
void ballgroup_kernel(const float* __restrict__ xyz, const float* __restrict__ feat,
                      float* out)
{
#pragma clang fp contract(off)
    __shared__ int idxl[4][KS];
    const int tid    = threadIdx.x;
    const int wv     = tid >> 6;
    const int lane   = tid & 63;
    const int center = blockIdx.x * 4 + wv;
    const int b      = center >> 11;          // / SPTS
    const int s      = center & (SPTS - 1);
    const float* xb  = xyz + (size_t)b * (NPTS * 3);
    const float* newxyz = out;                // written by fps_kernel earlier in stream
    const float cx = newxyz[(size_t)center * 3 + 0];
    const float cy = newxyz[(size_t)center * 3 + 1];
    const float cz = newxyz[(size_t)center * 3 + 2];

    if (lane == 0) idxl[wv][0] = 0;           // default when zero hits

    int cnt = 0;
    for (int nb = 0; nb < NPTS; nb += 64) {
        const int p = nb + lane;
        const float x = xb[p * 3 + 0];
        const float y = xb[p * 3 + 1];
        const float z = xb[p * 3 + 2];
        const float dx = cx - x, dy = cy - y, dz = cz - z;
        const float d2 = (dx * dx + dy * dy) + dz * dz;
        // f32 'd2 <= 0.04f' == numpy 'f32 d2 < float64(0.2*0.2)'
        const bool in = (d2 <= 0.04f);
        const unsigned long long mk = __ballot(in);
        if (in) {
            const int pos = cnt + __popcll(mk & ((1ull << lane) - 1ull));
            if (pos < KS) idxl[wv][pos] = p;
        }
        cnt += (int)__popcll(mk);
        if (cnt >= KS) break;                 // cnt is wave-uniform
    }
    const int cc = cnt < KS ? cnt : KS;

    // pad short lists with first hit (or 0), write padded list back
    int myidx = 0;
    if (lane < KS) {
        myidx = (lane < cc) ? idxl[wv][lane] : idxl[wv][0];
        idxl[wv][lane] = myidx;
    }

    float* grouped = out + OFF_GROUPED;
    const size_t chstride = (size_t)SPTS * KS;                    // 65536
    const size_t base67   = (size_t)b * 67 * chstride + (size_t)s * KS;

    // channels 0..2: recentered coords (point - center)
    if (lane < KS) {
        const float gx = xb[(size_t)myidx * 3 + 0] - cx;
        const float gy = xb[(size_t)myidx * 3 + 1] - cy;
        const float gz = xb[(size_t)myidx * 3 + 2] - cz;
        grouped[base67 + 0 * chstride + lane] = gx;
        grouped[base67 + 1 * chstride + lane] = gy;
        grouped[base67 + 2 * chstride + lane] = gz;
    }

    // channels 3..66: feature gather; lanes = (k, c-half)
    const int k    = lane & (KS - 1);
    const int half = lane >> 5;
    const int gi   = idxl[wv][k];
    const float* fb = feat + (size_t)b * CF * NPTS;
    const size_t obase = base67 + 3 * chstride + (size_t)k;
#pragma unroll 8
    for (int c0 = 0; c0 < 32; ++c0) {
        const int c = c0 * 2 + half;
        grouped[obase + (size_t)c * chstride] = fb[(size_t)c * NPTS + gi];
    }
}

extern "C" void kernel_launch(void* const* d_in, const int* in_sizes, int n_in,
                              void* d_out, int out_size, void* d_ws, size_t ws_size,
                              hipStream_t stream) {
    const float* xyz  = (const float*)d_in[0];
    const float* feat = (const float*)d_in[1];
    float* out = (float*)d_out;
    float* ws  = (float*)d_ws;    // needs 512 KB: vf4 sorted[4][8192]
    fps_kernel<<<dim3(BQ), dim3(FPS_T), 0, stream>>>(xyz, out, ws);
    ballgroup_kernel<<<dim3((BQ * SPTS) / 4), dim3(256), 0, stream>>>(xyz, feat, out);
}

// Round 5
// 4003.667 us; speedup vs baseline: 1.5195x; 1.5195x over previous
//
#include <hip/hip_runtime.h>

#define NPTS 8192
#define SPTS 2048
#define KS 32
#define CF 64
#define BQ 4
#define FPS_T 512
#define CPT 16               // groups per wave == slots per thread
#define NCELL 512            // 8x8x8 spatial grid (Morton order)

#define OFF_GROUPED 24576                    // B*S*3
#define GROUPED_SZ  17563648                 // B*67*S*K
#define OFF_FPSIDX  (OFF_GROUPED + GROUPED_SZ)

typedef __attribute__((ext_vector_type(4))) float vf4;
typedef unsigned long long u64;

__device__ __forceinline__ int mpart(int v) {   // spread 3 bits to 0,3,6
    return (v & 1) | ((v & 2) << 2) | ((v & 4) << 4);
}

// ---------------- FPS: one block per batch; Morton sort + wave-uniform group pruning ----------------
// d_ws: vf4 sorted[B][NPTS] = 512 KB. Layout: slot (w,k,l) = w*1024 + k*64 + l.
__global__ __launch_bounds__(FPS_T, 2)
void fps_kernel(const float* __restrict__ xyz, float* __restrict__ out,
                float* __restrict__ ws)
{
#pragma clang fp contract(off)
    __shared__ int hist[NCELL];
    __shared__ int scanbuf[NCELL];
    __shared__ int offs[NCELL];
    __shared__ u64 slots[2][8];

    const int b    = blockIdx.x;
    const int tid  = threadIdx.x;
    const int wv   = tid >> 6;
    const int lane = tid & 63;
    const float* xb = xyz + (size_t)b * (NPTS * 3);
    vf4* sorted = (vf4*)ws + (size_t)b * NPTS;
    const vf4* srt = sorted + (wv << 10);     // this wave's 1024-slot range

    // ---------- phase 1: counting sort by Morton cell ----------
    hist[tid] = 0;
    float a[3 * CPT];
    {
        const vf4* xb4 = (const vf4*)xb;
        vf4* av = (vf4*)a;
#pragma unroll
        for (int k = 0; k < 12; ++k) av[k] = xb4[tid * 12 + k];
    }
    int cell[CPT];
    __syncthreads();
#pragma unroll
    for (int j = 0; j < CPT; ++j) {
        const float x = a[3 * j + 0], y = a[3 * j + 1], z = a[3 * j + 2];
        int ix = (int)(x + 4.0f); ix = ix < 0 ? 0 : (ix > 7 ? 7 : ix);
        int iy = (int)(y + 4.0f); iy = iy < 0 ? 0 : (iy > 7 ? 7 : iy);
        int iz = (int)(z + 4.0f); iz = iz < 0 ? 0 : (iz > 7 ? 7 : iz);
        cell[j] = (mpart(ix) << 2) | (mpart(iy) << 1) | mpart(iz);
        atomicAdd(&hist[cell[j]], 1);
    }
    __syncthreads();
    {
        const int v = hist[tid];
        scanbuf[tid] = v;
        __syncthreads();
        for (int s = 1; s < NCELL; s <<= 1) {
            const int t = (tid >= s) ? scanbuf[tid - s] : 0;
            __syncthreads();
            scanbuf[tid] += t;
            __syncthreads();
        }
        offs[tid] = scanbuf[tid] - v;
    }
    __syncthreads();
#pragma unroll
    for (int j = 0; j < CPT; ++j) {
        const int pos = atomicAdd(&offs[cell[j]], 1);
        vf4 o;
        o.x = a[3 * j + 0]; o.y = a[3 * j + 1]; o.z = a[3 * j + 2];
        o.w = __int_as_float(tid * CPT + j);
        sorted[pos] = o;
    }
    __threadfence();
    __syncthreads();
    __threadfence();

    // ---------- phase 2: per-group bbox (lane l&15 caches group l&15's box) + oidx ----------
    float bxl = 0, bxh = 0, byl = 0, byh = 0, bzl = 0, bzh = 0;
    int oidx[CPT];
    float md[CPT];
#pragma unroll
    for (int k = 0; k < CPT; ++k) {
        const vf4 p = srt[(k << 6) | lane];
        oidx[k] = __float_as_int(p.w);
        md[k] = 1e10f;
        float xl = p.x, xh = p.x, yl = p.y, yh = p.y, zl = p.z, zh = p.z;
#pragma unroll
        for (int off = 32; off > 0; off >>= 1) {
            xl = fminf(xl, __shfl_xor(xl, off)); xh = fmaxf(xh, __shfl_xor(xh, off));
            yl = fminf(yl, __shfl_xor(yl, off)); yh = fmaxf(yh, __shfl_xor(yh, off));
            zl = fminf(zl, __shfl_xor(zl, off)); zh = fmaxf(zh, __shfl_xor(zh, off));
        }
        if ((lane & 15) == k) { bxl = xl; bxh = xh; byl = yl; byh = yh; bzl = zl; bzh = zh; }
    }

    float* newxyz = out;
    float* fpsidx = out + OFF_FPSIDX;

    float qx = xb[0], qy = xb[1], qz = xb[2];
    if (tid == 0) {
        fpsidx[(size_t)b * SPTS + 0] = 0.0f;
        newxyz[(size_t)b * SPTS * 3 + 0] = qx;
        newxyz[(size_t)b * SPTS * 3 + 1] = qy;
        newxyz[(size_t)b * SPTS * 3 + 2] = qz;
    }

    float wavemaxprev = 1e10f;
    u64 wkc = 0;

    // ---------- phase 3: FPS iterations ----------
    for (int i = 1; i < SPTS; ++i) {
        // parallel box pretest: lane l tests group l&15; conservative skip
        const float ddx = fmaxf(fmaxf(bxl - qx, qx - bxh), 0.0f);
        const float ddy = fmaxf(fmaxf(byl - qy, qy - byh), 0.0f);
        const float ddz = fmaxf(fmaxf(bzl - qz, qz - bzh), 0.0f);
        const float bb  = (ddx * ddx + ddy * ddy) + ddz * ddz;
        const unsigned mask = (unsigned)__ballot(bb * 0.999f < wavemaxprev) & 0xFFFFu;

        u64 wk;
        if (mask) {
            // update active groups: 1 coalesced 1KB vf4 load per group
#pragma unroll
            for (int k = 0; k < CPT; ++k) {
                if (mask & (1u << k)) {
                    const vf4 p = srt[(k << 6) | lane];
                    const float dx = p.x - qx;
                    const float dy = p.y - qy;
                    const float dz = p.z - qz;
                    const float d  = (dx * dx + dy * dy) + dz * dz;  // exact ref order
                    md[k] = fminf(md[k], d);
                }
            }
            // thread argmax over 16 slots: tree merge, tie -> smaller orig idx
            float td[CPT]; int to[CPT]; int ts[CPT];
#pragma unroll
            for (int k = 0; k < CPT; ++k) { td[k] = md[k]; to[k] = oidx[k]; ts[k] = (k << 6) | lane; }
#pragma unroll
            for (int st = 8; st >= 1; st >>= 1) {
#pragma unroll
                for (int j = 0; j < 8; ++j) {
                    if (j < st) {
                        const bool keep = (td[j] > td[j + st]) ||
                                          (td[j] == td[j + st] && to[j] < to[j + st]);
                        if (!keep) { td[j] = td[j + st]; to[j] = to[j + st]; ts[j] = ts[j + st]; }
                    }
                }
            }
            wk = ((u64)__float_as_uint(td[0]) << 32) |
                 ((u64)(unsigned)(NPTS - 1 - to[0]) << 13) |
                 (u64)(unsigned)((wv << 10) | ts[0]);
            // 64-lane butterfly max
#pragma unroll
            for (int off = 32; off > 0; off >>= 1) {
                const u64 o = __shfl_xor(wk, off);
                if (o > wk) wk = o;
            }
            wkc = wk;
        } else {
            wk = wkc;          // no md changed in this wave: cached key still exact
        }
        wavemaxprev = __uint_as_float((unsigned)(wk >> 32));

        if (lane == 0) slots[i & 1][wv] = wk;
        __syncthreads();       // the only barrier per iteration

        u64 s0 = slots[i & 1][0], s1 = slots[i & 1][1];
        u64 s2 = slots[i & 1][2], s3 = slots[i & 1][3];
        u64 s4 = slots[i & 1][4], s5 = slots[i & 1][5];
        u64 s6 = slots[i & 1][6], s7 = slots[i & 1][7];
        s0 = s0 > s1 ? s0 : s1;  s2 = s2 > s3 ? s2 : s3;
        s4 = s4 > s5 ? s4 : s5;  s6 = s6 > s7 ? s6 : s7;
        s0 = s0 > s2 ? s0 : s2;  s4 = s4 > s6 ? s4 : s6;
        const u64 g = s0 > s4 ? s0 : s4;

        const int winpos = (int)(g & 8191ull);
        const int worig  = (NPTS - 1) - (int)((g >> 13) & 8191ull);

        const vf4 q = sorted[winpos];        // lane-uniform broadcast load (L2)
        qx = q.x; qy = q.y; qz = q.z;

        if (tid == 0) {
            fpsidx[(size_t)b * SPTS + i] = (float)worig;
            const size_t o = ((size_t)b * SPTS + i) * 3;
            newxyz[o + 0] = qx; newxyz[o + 1] = qy; newxyz[o + 2] = qz;
        }
    }
}

// ---------------- ball query + grouping: one wave per center ----------------
__global__ __launch_bounds__(256)
void ballgroup_kernel(const float* __restrict__ xyz, const float* __restrict__ feat,
                      float* out)
{
#pragma clang fp contract(off)
    __shared__ int idxl[4][KS];
    const int tid    = threadIdx.x;
    const int wv     = tid >> 6;
    const int lane   = tid & 63;
    const int center = blockIdx.x * 4 + wv;
    const int b      = center >> 11;          // / SPTS
    const int s      = center & (SPTS - 1);
    const float* xb  = xyz + (size_t)b * (NPTS * 3);
    const float* newxyz = out;                // written by fps_kernel earlier in stream
    const float cx = newxyz[(size_t)center * 3 + 0];
    const float cy = newxyz[(size_t)center * 3 + 1];
    const float cz = newxyz[(size_t)center * 3 + 2];

    if (lane == 0) idxl[wv][0] = 0;           // default when zero hits

    int cnt = 0;
    for (int nb = 0; nb < NPTS; nb += 64) {
        const int p = nb + lane;
        const float x = xb[p * 3 + 0];
        const float y = xb[p * 3 + 1];
        const float z = xb[p * 3 + 2];
        const float dx = cx - x, dy = cy - y, dz = cz - z;
        const float d2 = (dx * dx + dy * dy) + dz * dz;
        const bool in = (d2 <= 0.04f);
        const unsigned long long mk = __ballot(in);
        if (in) {
            const int pos = cnt + __popcll(mk & ((1ull << lane) - 1ull));
            if (pos < KS) idxl[wv][pos] = p;
        }
        cnt += (int)__popcll(mk);
        if (cnt >= KS) break;                 // cnt is wave-uniform
    }
    const int cc = cnt < KS ? cnt : KS;

    int myidx = 0;
    if (lane < KS) {
        myidx = (lane < cc) ? idxl[wv][lane] : idxl[wv][0];
        idxl[wv][lane] = myidx;
    }

    float* grouped = out + OFF_GROUPED;
    const size_t chstride = (size_t)SPTS * KS;                    // 65536
    const size_t base67   = (size_t)b * 67 * chstride + (size_t)s * KS;

    if (lane < KS) {
        const float gx = xb[(size_t)myidx * 3 + 0] - cx;
        const float gy = xb[(size_t)myidx * 3 + 1] - cy;
        const float gz = xb[(size_t)myidx * 3 + 2] - cz;
        grouped[base67 + 0 * chstride + lane] = gx;
        grouped[base67 + 1 * chstride + lane] = gy;
        grouped[base67 + 2 * chstride + lane] = gz;
    }

    const int k    = lane & (KS - 1);
    const int half = lane >> 5;
    const int gi   = idxl[wv][k];
    const float* fb = feat + (size_t)b * CF * NPTS;
    const size_t obase = base67 + 3 * chstride + (size_t)k;
#pragma unroll 8
    for (int c0 = 0; c0 < 32; ++c0) {
        const int c = c0 * 2 + half;
        grouped[obase + (size_t)c * chstride] = fb[(size_t)c * NPTS + gi];
    }
}

extern "C" void kernel_launch(void* const* d_in, const int* in_sizes, int n_in,
                              void* d_out, int out_size, void* d_ws, size_t ws_size,
                              hipStream_t stream) {
    const float* xyz  = (const float*)d_in[0];
    const float* feat = (const float*)d_in[1];
    float* out = (float*)d_out;
    float* ws  = (float*)d_ws;    // 512 KB: vf4 sorted[4][8192]
    fps_kernel<<<dim3(BQ), dim3(FPS_T), 0, stream>>>(xyz, out, ws);
    ballgroup_kernel<<<dim3((BQ * SPTS) / 4), dim3(256), 0, stream>>>(xyz, feat, out);
}

// Round 6
// 3510.526 us; speedup vs baseline: 1.7329x; 1.1405x over previous
//
#include <hip/hip_runtime.h>

#define NPTS 8192
#define SPTS 2048
#define KS 32
#define CF 64
#define BQ 4
#define FPS_T 512
#define CPT 16               // groups per wave == slots per thread
#define NCELL 512            // 8x8x8 spatial grid (Morton order)

#define OFF_GROUPED 24576                    // B*S*3
#define GROUPED_SZ  17563648                 // B*67*S*K
#define OFF_FPSIDX  (OFF_GROUPED + GROUPED_SZ)

typedef __attribute__((ext_vector_type(4))) float vf4;
typedef unsigned long long u64;

__device__ __forceinline__ int mpart(int v) {   // spread 3 bits to 0,3,6
    return (v & 1) | ((v & 2) << 2) | ((v & 4) << 4);
}

// ---------------- FPS: one block per batch; LDS-resident Morton-sorted cloud,
// wave-uniform group pruning with decoupled (two-phase) LDS loads ----------------
__global__ __launch_bounds__(FPS_T, 2)
void fps_kernel(const float* __restrict__ xyz, float* __restrict__ out)
{
#pragma clang fp contract(off)
    __shared__ float sx[NPTS];          // 32 KB
    __shared__ float sy[NPTS];          // 32 KB
    __shared__ float sz[NPTS];          // 32 KB
    __shared__ int   so[NPTS];          // 32 KB (orig index per sorted slot)
    __shared__ int hist[NCELL];
    __shared__ int scanbuf[NCELL];
    __shared__ int offs[NCELL];
    __shared__ u64 slots[2][8];

    const int b    = blockIdx.x;
    const int tid  = threadIdx.x;
    const int wv   = tid >> 6;
    const int lane = tid & 63;
    const float* xb = xyz + (size_t)b * (NPTS * 3);
    const int wbase = wv << 10;         // this wave's 1024 sorted slots

    // ---------- phase 1: counting sort by Morton cell straight into LDS ----------
    hist[tid] = 0;
    float a[3 * CPT];
    {
        const vf4* xb4 = (const vf4*)xb;
        vf4* av = (vf4*)a;
#pragma unroll
        for (int k = 0; k < 12; ++k) av[k] = xb4[tid * 12 + k];
    }
    int cell[CPT];
    __syncthreads();
#pragma unroll
    for (int j = 0; j < CPT; ++j) {
        const float x = a[3 * j + 0], y = a[3 * j + 1], z = a[3 * j + 2];
        int ix = (int)(x + 4.0f); ix = ix < 0 ? 0 : (ix > 7 ? 7 : ix);
        int iy = (int)(y + 4.0f); iy = iy < 0 ? 0 : (iy > 7 ? 7 : iy);
        int iz = (int)(z + 4.0f); iz = iz < 0 ? 0 : (iz > 7 ? 7 : iz);
        cell[j] = (mpart(ix) << 2) | (mpart(iy) << 1) | mpart(iz);
        atomicAdd(&hist[cell[j]], 1);
    }
    __syncthreads();
    {
        const int v = hist[tid];
        scanbuf[tid] = v;
        __syncthreads();
        for (int s = 1; s < NCELL; s <<= 1) {
            const int t = (tid >= s) ? scanbuf[tid - s] : 0;
            __syncthreads();
            scanbuf[tid] += t;
            __syncthreads();
        }
        offs[tid] = scanbuf[tid] - v;
    }
    __syncthreads();
#pragma unroll
    for (int j = 0; j < CPT; ++j) {
        const int pos = atomicAdd(&offs[cell[j]], 1);
        sx[pos] = a[3 * j + 0];
        sy[pos] = a[3 * j + 1];
        sz[pos] = a[3 * j + 2];
        so[pos] = tid * CPT + j;
    }
    __syncthreads();

    // ---------- phase 2: per-group bbox (lane l caches group l&15's box) + oidx ----------
    float bxl = 0, bxh = 0, byl = 0, byh = 0, bzl = 0, bzh = 0;
    int oidx[CPT];
    float md[CPT];
#pragma unroll
    for (int k = 0; k < CPT; ++k) {
        const int adr = wbase + (k << 6) + lane;
        const float x = sx[adr], y = sy[adr], z = sz[adr];
        oidx[k] = so[adr];
        md[k] = 1e10f;
        float xl = x, xh = x, yl = y, yh = y, zl = z, zh = z;
#pragma unroll
        for (int off = 32; off > 0; off >>= 1) {
            xl = fminf(xl, __shfl_xor(xl, off)); xh = fmaxf(xh, __shfl_xor(xh, off));
            yl = fminf(yl, __shfl_xor(yl, off)); yh = fmaxf(yh, __shfl_xor(yh, off));
            zl = fminf(zl, __shfl_xor(zl, off)); zh = fmaxf(zh, __shfl_xor(zh, off));
        }
        if ((lane & 15) == k) { bxl = xl; bxh = xh; byl = yl; byh = yh; bzl = zl; bzh = zh; }
    }

    float* newxyz = out;
    float* fpsidx = out + OFF_FPSIDX;

    float qx = xb[0], qy = xb[1], qz = xb[2];
    if (tid == 0) {
        fpsidx[(size_t)b * SPTS + 0] = 0.0f;
        newxyz[(size_t)b * SPTS * 3 + 0] = qx;
        newxyz[(size_t)b * SPTS * 3 + 1] = qy;
        newxyz[(size_t)b * SPTS * 3 + 2] = qz;
    }

    float wavemaxprev = 1e10f;
    u64 wkc = 0;

    // ---------- phase 3: FPS iterations ----------
    for (int i = 1; i < SPTS; ++i) {
        // parallel box pretest: lane l tests group l&15; conservative skip
        const float ddx = fmaxf(fmaxf(bxl - qx, qx - bxh), 0.0f);
        const float ddy = fmaxf(fmaxf(byl - qy, qy - byh), 0.0f);
        const float ddz = fmaxf(fmaxf(bzl - qz, qz - bzh), 0.0f);
        const float bb  = (ddx * ddx + ddy * ddy) + ddz * ddz;
        const unsigned mask = (unsigned)__ballot(bb * 0.999f < wavemaxprev) & 0xFFFFu;

        u64 wk;
        if (mask) {
            // phase A: issue ALL active groups' LDS reads (no uses inside)
            float gx[CPT], gy[CPT], gz[CPT];
#pragma unroll
            for (int k = 0; k < CPT; ++k) {
                if (mask & (1u << k)) {
                    const int adr = wbase + (k << 6) + lane;
                    gx[k] = sx[adr];
                    gy[k] = sy[adr];
                    gz[k] = sz[adr];
                }
            }
            // phase B: one wait, then compute all active groups
#pragma unroll
            for (int k = 0; k < CPT; ++k) {
                if (mask & (1u << k)) {
                    const float dx = gx[k] - qx;
                    const float dy = gy[k] - qy;
                    const float dz = gz[k] - qz;
                    const float d  = (dx * dx + dy * dy) + dz * dz;  // exact ref order
                    md[k] = fminf(md[k], d);
                }
            }
            // thread argmax over 16 slots: tree merge, tie -> smaller orig idx
            float td[CPT]; int to[CPT]; int ts[CPT];
#pragma unroll
            for (int k = 0; k < CPT; ++k) { td[k] = md[k]; to[k] = oidx[k]; ts[k] = wbase + (k << 6) + lane; }
#pragma unroll
            for (int st = 8; st >= 1; st >>= 1) {
#pragma unroll
                for (int j = 0; j < 8; ++j) {
                    if (j < st) {
                        const bool keep = (td[j] > td[j + st]) ||
                                          (td[j] == td[j + st] && to[j] < to[j + st]);
                        if (!keep) { td[j] = td[j + st]; to[j] = to[j + st]; ts[j] = ts[j + st]; }
                    }
                }
            }
            wk = ((u64)__float_as_uint(td[0]) << 32) |
                 ((u64)(unsigned)(NPTS - 1 - to[0]) << 13) |
                 (u64)(unsigned)ts[0];
            // 64-lane butterfly max
#pragma unroll
            for (int off = 32; off > 0; off >>= 1) {
                const u64 o = __shfl_xor(wk, off);
                if (o > wk) wk = o;
            }
            wkc = wk;
        } else {
            wk = wkc;          // no md changed in this wave: cached key still exact
        }
        wavemaxprev = __uint_as_float((unsigned)(wk >> 32));

        if (lane == 0) slots[i & 1][wv] = wk;
        __syncthreads();       // the only barrier per iteration

        u64 s0 = slots[i & 1][0], s1 = slots[i & 1][1];
        u64 s2 = slots[i & 1][2], s3 = slots[i & 1][3];
        u64 s4 = slots[i & 1][4], s5 = slots[i & 1][5];
        u64 s6 = slots[i & 1][6], s7 = slots[i & 1][7];
        s0 = s0 > s1 ? s0 : s1;  s2 = s2 > s3 ? s2 : s3;
        s4 = s4 > s5 ? s4 : s5;  s6 = s6 > s7 ? s6 : s7;
        s0 = s0 > s2 ? s0 : s2;  s4 = s4 > s6 ? s4 : s6;
        const u64 g = s0 > s4 ? s0 : s4;

        const int winpos = (int)(g & 8191ull);
        const int worig  = (NPTS - 1) - (int)((g >> 13) & 8191ull);

        qx = sx[winpos];       // same-address LDS broadcast, ~120 cy
        qy = sy[winpos];
        qz = sz[winpos];

        if (tid == 0) {
            fpsidx[(size_t)b * SPTS + i] = (float)worig;
            const size_t o = ((size_t)b * SPTS + i) * 3;
            newxyz[o + 0] = qx; newxyz[o + 1] = qy; newxyz[o + 2] = qz;
        }
    }
}

// ---------------- ball query + grouping: one wave per center ----------------
__global__ __launch_bounds__(256)
void ballgroup_kernel(const float* __restrict__ xyz, const float* __restrict__ feat,
                      float* out)
{
#pragma clang fp contract(off)
    __shared__ int idxl[4][KS];
    const int tid    = threadIdx.x;
    const int wv     = tid >> 6;
    const int lane   = tid & 63;
    const int center = blockIdx.x * 4 + wv;
    const int b      = center >> 11;          // / SPTS
    const int s      = center & (SPTS - 1);
    const float* xb  = xyz + (size_t)b * (NPTS * 3);
    const float* newxyz = out;                // written by fps_kernel earlier in stream
    const float cx = newxyz[(size_t)center * 3 + 0];
    const float cy = newxyz[(size_t)center * 3 + 1];
    const float cz = newxyz[(size_t)center * 3 + 2];

    if (lane == 0) idxl[wv][0] = 0;           // default when zero hits

    int cnt = 0;
    for (int nb = 0; nb < NPTS; nb += 64) {
        const int p = nb + lane;
        const float x = xb[p * 3 + 0];
        const float y = xb[p * 3 + 1];
        const float z = xb[p * 3 + 2];
        const float dx = cx - x, dy = cy - y, dz = cz - z;
        const float d2 = (dx * dx + dy * dy) + dz * dz;
        const bool in = (d2 <= 0.04f);
        const unsigned long long mk = __ballot(in);
        if (in) {
            const int pos = cnt + __popcll(mk & ((1ull << lane) - 1ull));
            if (pos < KS) idxl[wv][pos] = p;
        }
        cnt += (int)__popcll(mk);
        if (cnt >= KS) break;                 // cnt is wave-uniform
    }
    const int cc = cnt < KS ? cnt : KS;

    int myidx = 0;
    if (lane < KS) {
        myidx = (lane < cc) ? idxl[wv][lane] : idxl[wv][0];
        idxl[wv][lane] = myidx;
    }

    float* grouped = out + OFF_GROUPED;
    const size_t chstride = (size_t)SPTS * KS;                    // 65536
    const size_t base67   = (size_t)b * 67 * chstride + (size_t)s * KS;

    if (lane < KS) {
        const float gx = xb[(size_t)myidx * 3 + 0] - cx;
        const float gy = xb[(size_t)myidx * 3 + 1] - cy;
        const float gz = xb[(size_t)myidx * 3 + 2] - cz;
        grouped[base67 + 0 * chstride + lane] = gx;
        grouped[base67 + 1 * chstride + lane] = gy;
        grouped[base67 + 2 * chstride + lane] = gz;
    }

    const int k    = lane & (KS - 1);
    const int half = lane >> 5;
    const int gi   = idxl[wv][k];
    const float* fb = feat + (size_t)b * CF * NPTS;
    const size_t obase = base67 + 3 * chstride + (size_t)k;
#pragma unroll 8
    for (int c0 = 0; c0 < 32; ++c0) {
        const int c = c0 * 2 + half;
        grouped[obase + (size_t)c * chstride] = fb[(size_t)c * NPTS + gi];
    }
}

extern "C" void kernel_launch(void* const* d_in, const int* in_sizes, int n_in,
                              void* d_out, int out_size, void* d_ws, size_t ws_size,
                              hipStream_t stream) {
    const float* xyz  = (const float*)d_in[0];
    const float* feat = (const float*)d_in[1];
    float* out = (float*)d_out;
    fps_kernel<<<dim3(BQ), dim3(FPS_T), 0, stream>>>(xyz, out);
    ballgroup_kernel<<<dim3((BQ * SPTS) / 4), dim3(256), 0, stream>>>(xyz, feat, out);
}

// Round 7
// 2582.542 us; speedup vs baseline: 2.3556x; 1.3593x over previous
//
#include <hip/hip_runtime.h>

#define NPTS 8192
#define SPTS 2048
#define KS 32
#define CF 64
#define BQ 4
#define FPS_T 512
#define PPT 16               // points per thread
#define NPAIR 8              // PPT/2, packed-f32 pairs
#define FPS_SHIFT 9          // log2(FPS_T)

#define OFF_GROUPED 24576                    // B*S*3
#define GROUPED_SZ  17563648                 // B*67*S*K
#define OFF_FPSIDX  (OFF_GROUPED + GROUPED_SZ)

typedef __attribute__((ext_vector_type(2))) float vf2;
typedef __attribute__((ext_vector_type(4))) float vf4;
typedef unsigned long long u64;

// ---------------- FPS: one block per batch; register-resident coords ----------------
// Coords pinned in VGPRs via per-iteration opaque asm redefinition (defeats both
// remat-from-global and spill-to-scratch). Winner broadcast via 128KB LDS mirror.
__global__ __launch_bounds__(FPS_T, 2)
void fps_kernel(const float* __restrict__ xyz, float* __restrict__ out)
{
#pragma clang fp contract(off)
    __shared__ vf4 qc[NPTS];             // 128 KB: coord mirror for winner broadcast
    __shared__ u64 slots[2][8];          // parity double-buffer; one slot per wave

    const int b    = blockIdx.x;
    const int tid  = threadIdx.x;
    const int wv   = tid >> 6;
    const int lane = tid & 63;
    const float* xb = xyz + (size_t)b * (NPTS * 3);

    // SoA packed pairs: pair h = points p0=tid+2h*512 (.x) and p1=p0+512 (.y)
    vf2 px[NPAIR], py[NPAIR], pz[NPAIR], mdp[NPAIR];
#pragma unroll
    for (int h = 0; h < NPAIR; ++h) {
        const int p0 = tid + ((2 * h) << FPS_SHIFT);
        const int p1 = p0 + FPS_T;
        px[h].x = xb[p0 * 3 + 0]; px[h].y = xb[p1 * 3 + 0];
        py[h].x = xb[p0 * 3 + 1]; py[h].y = xb[p1 * 3 + 1];
        pz[h].x = xb[p0 * 3 + 2]; pz[h].y = xb[p1 * 3 + 2];
        mdp[h].x = 1e10f; mdp[h].y = 1e10f;
        vf4 q0; q0.x = px[h].x; q0.y = py[h].x; q0.z = pz[h].x; q0.w = 0.0f;
        vf4 q1; q1.x = px[h].y; q1.y = py[h].y; q1.z = pz[h].y; q1.w = 0.0f;
        qc[p0] = q0; qc[p1] = q1;
    }

    float* newxyz = out;
    float* fpsidx = out + OFF_FPSIDX;

    float qx = xb[0], qy = xb[1], qz = xb[2];
    if (tid == 0) {
        fpsidx[(size_t)b * SPTS + 0] = 0.0f;
        newxyz[(size_t)b * SPTS * 3 + 0] = qx;
        newxyz[(size_t)b * SPTS * 3 + 1] = qy;
        newxyz[(size_t)b * SPTS * 3 + 2] = qz;
    }
    __syncthreads();                       // qc visible

    for (int i = 1; i < SPTS; ++i) {
        // pin coords in VGPRs THIS iteration: opaque redefinition kills remat,
        // and per-iter spill/reload would cost more than residency (budget=256)
#pragma unroll
        for (int h = 0; h < NPAIR; ++h)
            asm volatile("" : "+v"(px[h]), "+v"(py[h]), "+v"(pz[h]));

        vf2 q2x; q2x.x = qx; q2x.y = qx;
        vf2 q2y; q2y.x = qy; q2y.y = qy;
        vf2 q2z; q2z.x = qz; q2z.y = qz;

        // packed min-dist update: exact numpy order (dx*dx+dy*dy)+dz*dz, no fma
#pragma unroll
        for (int h = 0; h < NPAIR; ++h) {
            const vf2 dx = px[h] - q2x;
            const vf2 dy = py[h] - q2y;
            const vf2 dz = pz[h] - q2z;
            const vf2 sx = dx * dx;
            const vf2 sy = dy * dy;
            const vf2 sz = dz * dz;
            const vf2 t  = sx + sy;
            const vf2 d  = t + sz;
            mdp[h].x = fminf(mdp[h].x, d.x);
            mdp[h].y = fminf(mdp[h].y, d.y);
        }

        // max tree over 16 components
        float a0 = fmaxf(mdp[0].x, mdp[0].y), a1 = fmaxf(mdp[1].x, mdp[1].y);
        float a2 = fmaxf(mdp[2].x, mdp[2].y), a3 = fmaxf(mdp[3].x, mdp[3].y);
        float a4 = fmaxf(mdp[4].x, mdp[4].y), a5 = fmaxf(mdp[5].x, mdp[5].y);
        float a6 = fmaxf(mdp[6].x, mdp[6].y), a7 = fmaxf(mdp[7].x, mdp[7].y);
        a0 = fmaxf(a0, a1); a2 = fmaxf(a2, a3); a4 = fmaxf(a4, a5); a6 = fmaxf(a6, a7);
        a0 = fmaxf(a0, a2); a4 = fmaxf(a4, a6);
        const float best = fmaxf(a0, a4);

        // smallest owned j with md==best (descending overwrite -> first max)
        int bj = PPT - 1;
#pragma unroll
        for (int j = PPT - 2; j >= 0; --j) {
            const float v = (j & 1) ? mdp[j >> 1].y : mdp[j >> 1].x;
            if (v == best) bj = j;
        }
        const int bidx = tid + (bj << FPS_SHIFT);

        // wave argmax: f32 butterfly, then ballot+readlane (validated in R2)
        float wmax = best;
#pragma unroll
        for (int off = 32; off > 0; off >>= 1)
            wmax = fmaxf(wmax, __shfl_xor(wmax, off));

        const u64 m = __ballot(best == wmax);
        int widx_w;
        if (__popcll(m) == 1) {                  // unique owner: common case
            const int lane1 = __ffsll((long long)m) - 1;
            widx_w = __builtin_amdgcn_readlane(bidx, lane1);
        } else {                                 // exact dist tie: min global idx
            int cand = (best == wmax) ? bidx : 0x7FFFFFFF;
#pragma unroll
            for (int off = 32; off > 0; off >>= 1)
                cand = min(cand, __shfl_xor(cand, off));
            widx_w = cand;
        }

        if (lane == 0) {
            slots[i & 1][wv] = ((u64)__float_as_uint(wmax) << 32) |
                               (unsigned)(NPTS - 1 - widx_w);
        }
        __syncthreads();                         // the only barrier per iteration

        u64 s0 = slots[i & 1][0], s1 = slots[i & 1][1];
        u64 s2 = slots[i & 1][2], s3 = slots[i & 1][3];
        u64 s4 = slots[i & 1][4], s5 = slots[i & 1][5];
        u64 s6 = slots[i & 1][6], s7 = slots[i & 1][7];
        s0 = s0 > s1 ? s0 : s1;  s2 = s2 > s3 ? s2 : s3;
        s4 = s4 > s5 ? s4 : s5;  s6 = s6 > s7 ? s6 : s7;
        s0 = s0 > s2 ? s0 : s2;  s4 = s4 > s6 ? s4 : s6;
        const u64 g = s0 > s4 ? s0 : s4;
        const int widx = (NPTS - 1) - (int)(unsigned)(g & 0xffffffffull);

        // winner coords: one same-address ds_read_b128 broadcast (~130 cy)
        const vf4 q = qc[widx];
        qx = q.x; qy = q.y; qz = q.z;

        if (tid == 0) {
            fpsidx[(size_t)b * SPTS + i] = (float)widx;
            const size_t o = ((size_t)b * SPTS + i) * 3;
            newxyz[o + 0] = qx; newxyz[o + 1] = qy; newxyz[o + 2] = qz;
        }
    }
}

// ---------------- ball query + grouping: one wave per center ----------------
__global__ __launch_bounds__(256)
void ballgroup_kernel(const float* __restrict__ xyz, const float* __restrict__ feat,
                      float* out)
{
#pragma clang fp contract(off)
    __shared__ int idxl[4][KS];
    const int tid    = threadIdx.x;
    const int wv     = tid >> 6;
    const int lane   = tid & 63;
    const int center = blockIdx.x * 4 + wv;
    const int b      = center >> 11;          // / SPTS
    const int s      = center & (SPTS - 1);
    const float* xb  = xyz + (size_t)b * (NPTS * 3);
    const float* newxyz = out;                // written by fps_kernel earlier in stream
    const float cx = newxyz[(size_t)center * 3 + 0];
    const float cy = newxyz[(size_t)center * 3 + 1];
    const float cz = newxyz[(size_t)center * 3 + 2];

    if (lane == 0) idxl[wv][0] = 0;           // default when zero hits

    int cnt = 0;
    for (int nb = 0; nb < NPTS; nb += 64) {
        const int p = nb + lane;
        const float x = xb[p * 3 + 0];
        const float y = xb[p * 3 + 1];
        const float z = xb[p * 3 + 2];
        const float dx = cx - x, dy = cy - y, dz = cz - z;
        const float d2 = (dx * dx + dy * dy) + dz * dz;
        const bool in = (d2 <= 0.04f);
        const unsigned long long mk = __ballot(in);
        if (in) {
            const int pos = cnt + __popcll(mk & ((1ull << lane) - 1ull));
            if (pos < KS) idxl[wv][pos] = p;
        }
        cnt += (int)__popcll(mk);
        if (cnt >= KS) break;                 // cnt is wave-uniform
    }
    const int cc = cnt < KS ? cnt : KS;

    int myidx = 0;
    if (lane < KS) {
        myidx = (lane < cc) ? idxl[wv][lane] : idxl[wv][0];
        idxl[wv][lane] = myidx;
    }

    float* grouped = out + OFF_GROUPED;
    const size_t chstride = (size_t)SPTS * KS;                    // 65536
    const size_t base67   = (size_t)b * 67 * chstride + (size_t)s * KS;

    if (lane < KS) {
        const float gx = xb[(size_t)myidx * 3 + 0] - cx;
        const float gy = xb[(size_t)myidx * 3 + 1] - cy;
        const float gz = xb[(size_t)myidx * 3 + 2] - cz;
        grouped[base67 + 0 * chstride + lane] = gx;
        grouped[base67 + 1 * chstride + lane] = gy;
        grouped[base67 + 2 * chstride + lane] = gz;
    }

    const int k    = lane & (KS - 1);
    const int half = lane >> 5;
    const int gi   = idxl[wv][k];
    const float* fb = feat + (size_t)b * CF * NPTS;
    const size_t obase = base67 + 3 * chstride + (size_t)k;
#pragma unroll 8
    for (int c0 = 0; c0 < 32; ++c0) {
        const int c = c0 * 2 + half;
        grouped[obase + (size_t)c * chstride] = fb[(size_t)c * NPTS + gi];
    }
}

extern "C" void kernel_launch(void* const* d_in, const int* in_sizes, int n_in,
                              void* d_out, int out_size, void* d_ws, size_t ws_size,
                              hipStream_t stream) {
    const float* xyz  = (const float*)d_in[0];
    const float* feat = (const float*)d_in[1];
    float* out = (float*)d_out;
    fps_kernel<<<dim3(BQ), dim3(FPS_T), 0, stream>>>(xyz, out);
    ballgroup_kernel<<<dim3((BQ * SPTS) / 4), dim3(256), 0, stream>>>(xyz, feat, out);
}